// Round 15
// baseline (318.212 us; speedup 1.0000x reference)
//
#include <hip/hip_runtime.h>
#include <stdint.h>
#include <stddef.h>

// ---------- types ----------
typedef _Float16 half_t;
typedef half_t half8  __attribute__((ext_vector_type(8)));
typedef half_t half4v __attribute__((ext_vector_type(4)));
typedef float  f32x4  __attribute__((ext_vector_type(4)));

__device__ __forceinline__ float fast_sigmoid(float x) {
    float e = __builtin_amdgcn_exp2f(-1.44269504f * x);
    return __builtin_amdgcn_rcpf(1.0f + e);
}
__device__ __forceinline__ float fast_tanh(float x) {
    float e = __builtin_amdgcn_exp2f(2.88539008f * x);
    return 1.0f - 2.0f * __builtin_amdgcn_rcpf(1.0f + e);
}

// ---------------------------------------------------------------------------
// Prep: W [1024][256] f32 row-major -> MFMA-B fragment order, f16.
// Bijection (contiguous k): lane l, elem e of tile (T,kt) holds
//   B[k = kt*32 + (l>>4)*8 + e, j = T*16 + (l&15)].
// A-fragments from LDS use the SAME mapping (validated R1-R14, absmax 2e-3).
// ---------------------------------------------------------------------------
__global__ __launch_bounds__(64) void shuffle_w_kernel(
    const float* __restrict__ W, half_t* __restrict__ out)
{
    const int blk = blockIdx.x;         // 512 = 64 T * 8 kt
    const int T = blk >> 3, kt = blk & 7;
    const int l = threadIdx.x;
    const int j = T * 16 + (l & 15);
    const int k0 = kt * 32 + ((l >> 4) << 3);
    half8 v;
#pragma unroll
    for (int e = 0; e < 8; ++e) v[e] = (half_t)W[j * 256 + k0 + e];
    *reinterpret_cast<half8*>(out + (size_t)(blk * 64 + l) * 8) = v;
}

// ---------------------------------------------------------------------------
// 2-gate (4 N-tile) GEMM pass, B double-buffered, kt FULLY UNROLLED with a
// sched_barrier(0) fence per window (fences = the proven anti-hoist; full
// unroll makes the cowork window index compile-time -- rule #20).
// cowork(kt) is VALU work injected into each window's MFMA shadow.
// ---------------------------------------------------------------------------
template <typename CoWork>
__device__ __forceinline__ void gemm_pass(
    f32x4* acc, const half_t* __restrict__ lhx,
    const half_t* Ws, int Ta, int Tb, int Tc, int Td,
    int lm, int lg, int l, CoWork&& cowork)
{
    asm volatile("" : "+v"(Ws));   // anti-LICM: recompute bp per call
    const half_t* bp[4] = {
        Ws + (size_t)((Ta * 8) * 64 + l) * 8,
        Ws + (size_t)((Tb * 8) * 64 + l) * 8,
        Ws + (size_t)((Tc * 8) * 64 + l) * 8,
        Ws + (size_t)((Td * 8) * 64 + l) * 8 };
    half8 bC[4], bN[4];
#pragma unroll
    for (int n = 0; n < 4; ++n) bC[n] = *reinterpret_cast<const half8*>(bp[n]);

#pragma unroll
    for (int kt = 0; kt < 8; ++kt) {
        if (kt < 7) {
#pragma unroll
            for (int n = 0; n < 4; ++n)
                bN[n] = *reinterpret_cast<const half8*>(bp[n] + (kt + 1) * 512);
        }
        half8 a[4];
#pragma unroll
        for (int mt = 0; mt < 4; ++mt) {
            const int p = mt * 16 + lm;
            const int k = (kt * 32 + lg * 8) ^ ((p & 7) << 4);
            a[mt] = *reinterpret_cast<const half8*>(&lhx[p * 256 + k]);
        }
#pragma unroll
        for (int n = 0; n < 4; ++n)
#pragma unroll
            for (int mt = 0; mt < 4; ++mt)
                acc[mt * 4 + n] = __builtin_amdgcn_mfma_f32_16x16x32_f16(
                    a[mt], bC[n], acc[mt * 4 + n], 0, 0, 0);
        cowork(kt);               // VALU fills the MFMA shadow
        if (kt < 7) {
#pragma unroll
            for (int n = 0; n < 4; ++n) bC[n] = bN[n];
        }
        __builtin_amdgcn_sched_barrier(0);   // window boundary (anti-hoist)
    }
}

// ---------------------------------------------------------------------------
// Persistent LSTM: block = 64 rows x 16 steps, 8 waves (512 threads).
// R14 base (253 us, zero spills) + R15 software pipelining:
//   dual acc (accA=f,o / accB=i,g -> 128 AGPR), head(t-1) co-worked into
//   gemmA windows (W_lin float4s pipelined 1 window ahead), epiA co-worked
//   into gemmB windows (og stores sig(o), moving 32 sigmoids off epiB).
// Arch ledger: gemmB peak = b 32 + a 16 + cxr 32 + og 16 + addr ~15 = ~111.
// LDS: hx 32 KB (XOR-swizzled) + xp 128 KB = 160 KB, 1 blk/CU.
// ---------------------------------------------------------------------------
__global__ __launch_bounds__(512)
void lstm_kernel(
    const float* __restrict__ x,      // [8][256][1600]
    const float* __restrict__ hx0,    // [12800][256]
    const float* __restrict__ cx0,    // [12800][256]
    const float* __restrict__ b_ih,   // [1024]
    const float* __restrict__ b_hh,   // [1024]
    const float* __restrict__ W_lin,  // [2][256]
    const float* __restrict__ b_lin,  // [2]
    const half_t* __restrict__ Wih_s, // shuffled f16
    const half_t* __restrict__ Whh_s, // shuffled f16
    float* __restrict__ out)          // [12800][16][2]
{
    __shared__ __align__(16) half_t lds_hx[64 * 256];        // 32 KB
    __shared__ __align__(16) half_t lds_xp[8 * 32 * 64 * 4]; // 128 KB

    const int tid = threadIdx.x;
    const int w  = tid >> 6;   // wave 0..7 owns h-cols [w*32, w*32+32)
    const int l  = tid & 63;
    const int lm = l & 15;
    const int lg = l >> 4;
    const int w2 = w * 2;

    const int row0 = blockIdx.x * 64;     // 200 blocks * 64 rows
    const int bb_  = row0 / 1600;
    const int p0   = row0 % 1600;

    // ---- stage x tile into lds_hx, f16 swizzled (coalesced on p) ----
    {
        const float* xin = x + (size_t)bb_ * 409600 + p0;   // x[b][c][p0+p]
        for (int it = 0; it < 32; ++it) {
            int idx = it * 512 + tid;
            int p = idx & 63, c = idx >> 6;
            lds_hx[p * 256 + (c ^ ((p & 7) << 4))] = (half_t)xin[c * 1600 + p];
        }
    }
    __syncthreads();

    f32x4 accA[16], accB[16];
    auto nocw = [](int) {};

    // ---- phase 0: x_proj = x @ W_ih^T + b_ih + b_hh, 2 passes -> LDS ----
#pragma unroll 1
    for (int pass = 0; pass < 2; ++pass) {
        const int gA = pass ? 0 : 16;     // pass0:(f,o) pass1:(i,g)
        const int gB = pass ? 32 : 48;
        const int Ta = gA + w2, Tb = Ta + 1;
        const int Tc = gB + w2, Td = Tc + 1;
        const int Tt[4] = {Ta, Tb, Tc, Td};
#pragma unroll
        for (int n = 0; n < 4; ++n) {
            int col = Tt[n] * 16 + lm;
            float bias = b_ih[col] + b_hh[col];
#pragma unroll
            for (int mt = 0; mt < 4; ++mt)
                accA[mt * 4 + n] = (f32x4){bias, bias, bias, bias};
        }
        gemm_pass(accA, lds_hx, Wih_s, Ta, Tb, Tc, Td, lm, lg, l, nocw);
#pragma unroll
        for (int f = 0; f < 16; ++f) {
            half4v xv;
#pragma unroll
            for (int r = 0; r < 4; ++r) xv[r] = (half_t)accA[f][r];
            *reinterpret_cast<half4v*>(
                &lds_xp[((w * 32 + pass * 16 + f) * 64 + l) * 4]) = xv;
        }
    }
    __syncthreads();   // x tile fully consumed, xp written

    // ---- stage h0 into lds_hx (coalesced on c); cx into registers ----
    {
        const float* hin = hx0 + (size_t)row0 * 256;
        for (int it = 0; it < 32; ++it) {
            int idx = it * 512 + tid;
            int c = idx & 255, p = idx >> 8;
            lds_hx[p * 256 + (c ^ ((p & 7) << 4))] = (half_t)hin[p * 256 + c];
        }
    }
    float cxr[32];
#pragma unroll
    for (int mt = 0; mt < 4; ++mt)
#pragma unroll
        for (int j = 0; j < 2; ++j)
#pragma unroll
            for (int r = 0; r < 4; ++r) {
                int p = mt * 16 + lg * 4 + r;
                int c = w * 32 + j * 16 + lm;
                cxr[(mt * 2 + j) * 4 + r] = cx0[(size_t)(row0 + p) * 256 + c];
            }
    const float blin0 = b_lin[0], blin1 = b_lin[1];
    const int ph = tid >> 3;          // head: row 0..63
    const int ho = (tid >> 2) & 1;    // head: output 0..1
    const int hq = tid & 3;           // head: quarter of 256 h-cols
    __syncthreads();

    // ---------------- 16 recurrent steps ----------------
#pragma unroll 1
    for (int t = 0; t < 16; ++t) {
        half4v og[8];   // sig(o-gate), f16

        // head(t-1) state: W_lin float4s pipelined one window ahead
        const float* wl = W_lin + ho * 256 + hq * 64;
        asm volatile("" : "+v"(wl));
        float hs = 0.0f;
        float4 hwv0, hwv1;
        if (t > 0) {
            hwv0 = *reinterpret_cast<const float4*>(wl + 0);
            hwv1 = *reinterpret_cast<const float4*>(wl + 4);
        }
        auto head_cw = [&](int wi) {
            if (t > 0) {
#pragma unroll
                for (int ii = 0; ii < 2; ++ii) {
                    int cb = wi * 2 + ii;
                    int c0 = hq * 64 + cb * 4;
                    half4v u = *reinterpret_cast<const half4v*>(
                        &lds_hx[ph * 256 + (c0 ^ ((ph & 7) << 4))]);
                    float4 wv = ii ? hwv1 : hwv0;
                    if (cb + 2 < 16) {    // prefetch next window's float4
                        float4 nx = *reinterpret_cast<const float4*>(
                            wl + (cb + 2) * 4);
                        if (ii) hwv1 = nx; else hwv0 = nx;
                    }
                    float h0 = (float)u[0], h1 = (float)u[1];
                    float h2 = (float)u[2], h3 = (float)u[3];
                    hs += fmaxf(h0, 0.01f * h0) * wv.x;
                    hs += fmaxf(h1, 0.01f * h1) * wv.y;
                    hs += fmaxf(h2, 0.01f * h2) * wv.z;
                    hs += fmaxf(h3, 0.01f * h3) * wv.w;
                }
            }
        };

        // ---- pass A: gates (f,o) into accA; head(t-1) in the shadow ----
#pragma unroll
        for (int fc = 0; fc < 16; fc += 4) {
#pragma unroll
            for (int f = fc; f < fc + 4; ++f) {
                half4v u = *reinterpret_cast<const half4v*>(
                    &lds_xp[((w * 32 + f) * 64 + l) * 4]);
#pragma unroll
                for (int r = 0; r < 4; ++r) accA[f][r] = (float)u[r];
            }
            __builtin_amdgcn_sched_barrier(0);
        }
        gemm_pass(accA, lds_hx, Whh_s, 16 + w2, 17 + w2, 48 + w2, 49 + w2,
                  lm, lg, l, head_cw);
        if (t > 0) {
            hs += __shfl_xor(hs, 1);
            hs += __shfl_xor(hs, 2);
            if (hq == 0)
                out[((size_t)(row0 + ph) * 16 + (t - 1)) * 2 + ho] =
                    hs + (ho ? blin1 : blin0);
        }

        // epiA as cowork for pass B: consume accA, fold sig(f) into cxr,
        // stash sig(o) as f16 (4 values per window, all indices constexpr)
        auto epiA_cw = [&](int wi) {
#pragma unroll
            for (int k = 0; k < 4; ++k) {
                int v = wi * 4 + k;
                int mt = v >> 3, j = (v >> 2) & 1, r = v & 3;
                float fv = accA[mt * 4 + 0 + j][r];
                float ov = accA[mt * 4 + 2 + j][r];
                cxr[(mt * 2 + j) * 4 + r] *= fast_sigmoid(fv);
                og[mt * 2 + j][r] = (half_t)fast_sigmoid(ov);
            }
        };

        // ---- pass B: gates (i,g) into accB; epiA in the shadow ----
#pragma unroll
        for (int fc = 0; fc < 16; fc += 4) {
#pragma unroll
            for (int f = fc; f < fc + 4; ++f) {
                half4v u = *reinterpret_cast<const half4v*>(
                    &lds_xp[((w * 32 + 16 + f) * 64 + l) * 4]);
#pragma unroll
                for (int r = 0; r < 4; ++r) accB[f][r] = (float)u[r];
            }
            __builtin_amdgcn_sched_barrier(0);
        }
        gemm_pass(accB, lds_hx, Whh_s, w2, w2 + 1, 32 + w2, 33 + w2,
                  lm, lg, l, epiA_cw);

        __syncthreads();   // all waves finished reading lds_hx(t)

        // epiB: cell update; write hx(t+1) into lds_hx (f16, swizzled)
#pragma unroll
        for (int mt = 0; mt < 4; ++mt)
#pragma unroll
            for (int j = 0; j < 2; ++j)
#pragma unroll
                for (int r = 0; r < 4; ++r) {
                    const int ci = (mt * 2 + j) * 4 + r;
                    float iv = accB[mt * 4 + 0 + j][r];
                    float gv = accB[mt * 4 + 2 + j][r];
                    float cxn = cxr[ci] + fast_sigmoid(iv) * fast_tanh(gv);
                    cxr[ci] = cxn;
                    float h = (float)og[mt * 2 + j][r] * fast_tanh(cxn);
                    int p  = mt * 16 + lg * 4 + r;
                    int cc = w * 32 + j * 16 + lm;
                    lds_hx[p * 256 + (cc ^ ((p & 7) << 4))] = (half_t)h;
                }
        __syncthreads();   // hx(t+1) visible to all (next gemmA + head)
    }

    // ---- final head (t = 15) ----
    {
        const float* wl = W_lin + ho * 256 + hq * 64;
        asm volatile("" : "+v"(wl));
        float s = 0.0f;
#pragma unroll 2
        for (int cb = 0; cb < 16; ++cb) {
            int c0 = hq * 64 + cb * 4;
            half4v u = *reinterpret_cast<const half4v*>(
                &lds_hx[ph * 256 + (c0 ^ ((ph & 7) << 4))]);
            float4 wv = *reinterpret_cast<const float4*>(wl + cb * 4);
            float h0 = (float)u[0], h1 = (float)u[1];
            float h2 = (float)u[2], h3 = (float)u[3];
            s += fmaxf(h0, 0.01f * h0) * wv.x;
            s += fmaxf(h1, 0.01f * h1) * wv.y;
            s += fmaxf(h2, 0.01f * h2) * wv.z;
            s += fmaxf(h3, 0.01f * h3) * wv.w;
        }
        s += __shfl_xor(s, 1);
        s += __shfl_xor(s, 2);
        if (hq == 0)
            out[((size_t)(row0 + ph) * 16 + 15) * 2 + ho] =
                s + (ho ? blin1 : blin0);
    }
}

// ---------------------------------------------------------------------------
extern "C" void kernel_launch(void* const* d_in, const int* in_sizes, int n_in,
                              void* d_out, int out_size, void* d_ws, size_t ws_size,
                              hipStream_t stream)
{
    const float* x    = (const float*)d_in[0];
    const float* hx   = (const float*)d_in[1];
    const float* cx   = (const float*)d_in[2];
    const float* Wih  = (const float*)d_in[3];
    const float* Whh  = (const float*)d_in[4];
    const float* bih  = (const float*)d_in[5];
    const float* bhh  = (const float*)d_in[6];
    const float* Wlin = (const float*)d_in[7];
    const float* blin = (const float*)d_in[8];
    float* out = (float*)d_out;

    half_t* wih_s = (half_t*)d_ws;             // 512 KB
    half_t* whh_s = wih_s + 1024 * 256;        // 512 KB

    shuffle_w_kernel<<<512, 64, 0, stream>>>(Wih, wih_s);
    shuffle_w_kernel<<<512, 64, 0, stream>>>(Whh, whh_s);
    lstm_kernel<<<200, 512, 0, stream>>>(x, hx, cx, bih, bhh, Wlin, blin,
                                         wih_s, whh_s, out);
}

// Round 16
// 245.071 us; speedup vs baseline: 1.2984x; 1.2984x over previous
//
#include <hip/hip_runtime.h>
#include <stdint.h>
#include <stddef.h>

// ---------- types ----------
typedef _Float16 half_t;
typedef half_t half8  __attribute__((ext_vector_type(8)));
typedef half_t half4v __attribute__((ext_vector_type(4)));
typedef float  f32x4  __attribute__((ext_vector_type(4)));

__device__ __forceinline__ float fast_sigmoid(float x) {
    float e = __builtin_amdgcn_exp2f(-1.44269504f * x);
    return __builtin_amdgcn_rcpf(1.0f + e);
}
__device__ __forceinline__ float fast_tanh(float x) {
    float e = __builtin_amdgcn_exp2f(2.88539008f * x);
    return 1.0f - 2.0f * __builtin_amdgcn_rcpf(1.0f + e);
}

// ---------------------------------------------------------------------------
// Prep: W [1024][256] f32 row-major -> MFMA-B fragment order, f16.
// Bijection (contiguous k): lane l, elem e of tile (T,kt) holds
//   B[k = kt*32 + (l>>4)*8 + e, j = T*16 + (l&15)].
// A-fragments from LDS use the SAME mapping (validated R1-R15, absmax 2e-3).
// ---------------------------------------------------------------------------
__global__ __launch_bounds__(64) void shuffle_w_kernel(
    const float* __restrict__ W, half_t* __restrict__ out)
{
    const int blk = blockIdx.x;         // 512 = 64 T * 8 kt
    const int T = blk >> 3, kt = blk & 7;
    const int l = threadIdx.x;
    const int j = T * 16 + (l & 15);
    const int k0 = kt * 32 + ((l >> 4) << 3);
    half8 v;
#pragma unroll
    for (int e = 0; e < 8; ++e) v[e] = (half_t)W[j * 256 + k0 + e];
    *reinterpret_cast<half8*>(out + (size_t)(blk * 64 + l) * 8) = v;
}

// ---------------------------------------------------------------------------
// 2-gate (4 N-tile) GEMM pass with B double-buffer (R12/R14-validated):
// kt loop PINNED (unroll 1 + sched_barrier per window) -- the proven
// anti-spill structure. R16 adds a cowork(window) callback invoked in each
// window's MFMA shadow; cowork must carry near-zero register state
// (R15 lesson: dual-acc cowork re-spilled, -65 us).
// ---------------------------------------------------------------------------
template <typename CoWork>
__device__ __forceinline__ void gemm_pass(
    f32x4* acc, const half_t* __restrict__ lhx,
    const half_t* Ws, int Ta, int Tb, int Tc, int Td,
    int lm, int lg, int l, CoWork&& cowork)
{
    asm volatile("" : "+v"(Ws));   // anti-LICM: recompute bp per call
    const half_t* bp[4] = {
        Ws + (size_t)((Ta * 8) * 64 + l) * 8,
        Ws + (size_t)((Tb * 8) * 64 + l) * 8,
        Ws + (size_t)((Tc * 8) * 64 + l) * 8,
        Ws + (size_t)((Td * 8) * 64 + l) * 8 };
    half8 bA[4], bB[4];
#pragma unroll
    for (int n = 0; n < 4; ++n) bA[n] = *reinterpret_cast<const half8*>(bp[n]);

#pragma unroll 1
    for (int kt2 = 0; kt2 < 4; ++kt2) {
        const int kt = kt2 * 2;
        // prefetch b(kt+1); MFMA(kt) with bA; cowork window kt
#pragma unroll
        for (int n = 0; n < 4; ++n)
            bB[n] = *reinterpret_cast<const half8*>(bp[n] + (kt + 1) * 512);
        {
            half8 a[4];
#pragma unroll
            for (int mt = 0; mt < 4; ++mt) {
                const int p = mt * 16 + lm;
                const int k = (kt * 32 + lg * 8) ^ ((p & 7) << 4);
                a[mt] = *reinterpret_cast<const half8*>(&lhx[p * 256 + k]);
            }
#pragma unroll
            for (int n = 0; n < 4; ++n)
#pragma unroll
                for (int mt = 0; mt < 4; ++mt)
                    acc[mt * 4 + n] = __builtin_amdgcn_mfma_f32_16x16x32_f16(
                        a[mt], bA[n], acc[mt * 4 + n], 0, 0, 0);
        }
        cowork(kt);
        __builtin_amdgcn_sched_barrier(0);
        // prefetch b(kt+2) (wrap harmless); MFMA(kt+1) with bB; cowork kt+1
#pragma unroll
        for (int n = 0; n < 4; ++n)
            bA[n] = *reinterpret_cast<const half8*>(bp[n] + ((kt + 2) & 7) * 512);
        {
            half8 a[4];
#pragma unroll
            for (int mt = 0; mt < 4; ++mt) {
                const int p = mt * 16 + lm;
                const int k = ((kt + 1) * 32 + lg * 8) ^ ((p & 7) << 4);
                a[mt] = *reinterpret_cast<const half8*>(&lhx[p * 256 + k]);
            }
#pragma unroll
            for (int n = 0; n < 4; ++n)
#pragma unroll
                for (int mt = 0; mt < 4; ++mt)
                    acc[mt * 4 + n] = __builtin_amdgcn_mfma_f32_16x16x32_f16(
                        a[mt], bB[n], acc[mt * 4 + n], 0, 0, 0);
        }
        cowork(kt + 1);
        __builtin_amdgcn_sched_barrier(0);
    }
}

// ---------------------------------------------------------------------------
// Persistent LSTM: block = 64 rows x 16 steps, 8 waves (512 threads).
// R14 base (253 us, ZERO spills) + head(t-1) co-worked into gemmA's MFMA
// shadow (~12 arch regs of state: hs + 2 pipelined W_lin float4s + ptr).
// The dedicated head phase disappears; final head for t=15 after the loop.
// Arch ledger pass A: cxr 32 + b dbuf 32 + a 16 + head 12 + addr ~15 = ~107.
// Pass B unchanged from R14 (~111). LDS: hx 32 KB + xp 128 KB = 160 KB.
// ---------------------------------------------------------------------------
__global__ __launch_bounds__(512)
void lstm_kernel(
    const float* __restrict__ x,      // [8][256][1600]
    const float* __restrict__ hx0,    // [12800][256]
    const float* __restrict__ cx0,    // [12800][256]
    const float* __restrict__ b_ih,   // [1024]
    const float* __restrict__ b_hh,   // [1024]
    const float* __restrict__ W_lin,  // [2][256]
    const float* __restrict__ b_lin,  // [2]
    const half_t* __restrict__ Wih_s, // shuffled f16
    const half_t* __restrict__ Whh_s, // shuffled f16
    float* __restrict__ out)          // [12800][16][2]
{
    __shared__ __align__(16) half_t lds_hx[64 * 256];        // 32 KB
    __shared__ __align__(16) half_t lds_xp[8 * 32 * 64 * 4]; // 128 KB

    const int tid = threadIdx.x;
    const int w  = tid >> 6;   // wave 0..7 owns h-cols [w*32, w*32+32)
    const int l  = tid & 63;
    const int lm = l & 15;
    const int lg = l >> 4;
    const int w2 = w * 2;

    const int row0 = blockIdx.x * 64;     // 200 blocks * 64 rows
    const int bb_  = row0 / 1600;
    const int p0   = row0 % 1600;

    // ---- stage x tile into lds_hx, f16 swizzled (coalesced on p) ----
    {
        const float* xin = x + (size_t)bb_ * 409600 + p0;   // x[b][c][p0+p]
        for (int it = 0; it < 32; ++it) {
            int idx = it * 512 + tid;
            int p = idx & 63, c = idx >> 6;
            lds_hx[p * 256 + (c ^ ((p & 7) << 4))] = (half_t)xin[c * 1600 + p];
        }
    }
    __syncthreads();

    f32x4 acc[16];
    auto nocw = [](int) {};

    // ---- phase 0: x_proj = x @ W_ih^T + b_ih + b_hh, 2 passes -> LDS ----
#pragma unroll 1
    for (int pass = 0; pass < 2; ++pass) {
        const int gA = pass ? 0 : 16;     // pass0:(f,o) pass1:(i,g)
        const int gB = pass ? 32 : 48;
        const int Ta = gA + w2, Tb = Ta + 1;
        const int Tc = gB + w2, Td = Tc + 1;
        const int Tt[4] = {Ta, Tb, Tc, Td};
#pragma unroll
        for (int n = 0; n < 4; ++n) {
            int col = Tt[n] * 16 + lm;
            float bias = b_ih[col] + b_hh[col];
#pragma unroll
            for (int mt = 0; mt < 4; ++mt)
                acc[mt * 4 + n] = (f32x4){bias, bias, bias, bias};
        }
        gemm_pass(acc, lds_hx, Wih_s, Ta, Tb, Tc, Td, lm, lg, l, nocw);
#pragma unroll
        for (int f = 0; f < 16; ++f) {
            half4v xv;
#pragma unroll
            for (int r = 0; r < 4; ++r) xv[r] = (half_t)acc[f][r];
            *reinterpret_cast<half4v*>(
                &lds_xp[((w * 32 + pass * 16 + f) * 64 + l) * 4]) = xv;
        }
    }
    __syncthreads();   // x tile fully consumed, xp written

    // ---- stage h0 into lds_hx (coalesced on c); cx into registers ----
    {
        const float* hin = hx0 + (size_t)row0 * 256;
        for (int it = 0; it < 32; ++it) {
            int idx = it * 512 + tid;
            int c = idx & 255, p = idx >> 8;
            lds_hx[p * 256 + (c ^ ((p & 7) << 4))] = (half_t)hin[p * 256 + c];
        }
    }
    float cxr[32];
#pragma unroll
    for (int mt = 0; mt < 4; ++mt)
#pragma unroll
        for (int j = 0; j < 2; ++j)
#pragma unroll
            for (int r = 0; r < 4; ++r) {
                int p = mt * 16 + lg * 4 + r;
                int c = w * 32 + j * 16 + lm;
                cxr[(mt * 2 + j) * 4 + r] = cx0[(size_t)(row0 + p) * 256 + c];
            }
    const float blin0 = b_lin[0], blin1 = b_lin[1];
    const int ph = tid >> 3;          // head: row 0..63
    const int ho = (tid >> 2) & 1;    // head: output 0..1
    const int hq = tid & 3;           // head: quarter of 256 h-cols
    __syncthreads();

    // ---------------- 16 recurrent steps ----------------
#pragma unroll 1
    for (int t = 0; t < 16; ++t) {
        half4v og[8];   // o-gate preactivations, f16 (R5-validated)

        // head(t-1) state: W_lin float4s pipelined one window ahead
        const float* wl = W_lin + ho * 256 + hq * 64;
        asm volatile("" : "+v"(wl));
        float hs = 0.0f;
        float4 hwv0, hwv1;
        if (t > 0) {
            hwv0 = *reinterpret_cast<const float4*>(wl + 0);
            hwv1 = *reinterpret_cast<const float4*>(wl + 4);
        }
        auto head_cw = [&](int wi) {
            if (t > 0) {
#pragma unroll
                for (int ii = 0; ii < 2; ++ii) {
                    int cb = wi * 2 + ii;
                    int c0 = hq * 64 + cb * 4;
                    half4v u = *reinterpret_cast<const half4v*>(
                        &lds_hx[ph * 256 + (c0 ^ ((ph & 7) << 4))]);
                    float4 wv = ii ? hwv1 : hwv0;
                    if (cb + 2 < 16) {   // prefetch next window's float4
                        float4 nx = *reinterpret_cast<const float4*>(
                            wl + (cb + 2) * 4);
                        if (ii) hwv1 = nx; else hwv0 = nx;
                    }
                    float h0 = (float)u[0], h1 = (float)u[1];
                    float h2 = (float)u[2], h3 = (float)u[3];
                    hs += fmaxf(h0, 0.01f * h0) * wv.x;
                    hs += fmaxf(h1, 0.01f * h1) * wv.y;
                    hs += fmaxf(h2, 0.01f * h2) * wv.z;
                    hs += fmaxf(h3, 0.01f * h3) * wv.w;
                }
            }
        };

        // ---- pass A: gates (f,o); acc init CHUNKED; head in the shadow ----
#pragma unroll
        for (int fc = 0; fc < 16; fc += 4) {
#pragma unroll
            for (int f = fc; f < fc + 4; ++f) {
                half4v u = *reinterpret_cast<const half4v*>(
                    &lds_xp[((w * 32 + f) * 64 + l) * 4]);
#pragma unroll
                for (int r = 0; r < 4; ++r) acc[f][r] = (float)u[r];
            }
            __builtin_amdgcn_sched_barrier(0);
        }
        gemm_pass(acc, lds_hx, Whh_s, 16 + w2, 17 + w2, 48 + w2, 49 + w2,
                  lm, lg, l, head_cw);
        if (t > 0) {
            hs += __shfl_xor(hs, 1);
            hs += __shfl_xor(hs, 2);
            if (hq == 0)
                out[((size_t)(row0 + ph) * 16 + (t - 1)) * 2 + ho] =
                    hs + (ho ? blin1 : blin0);
        }

        // epiA: fold sig(f) into cxr, stash o-preact f16 (as R14)
#pragma unroll
        for (int mt = 0; mt < 4; ++mt)
#pragma unroll
            for (int j = 0; j < 2; ++j)
#pragma unroll
                for (int r = 0; r < 4; ++r) {
                    float fv = acc[mt * 4 + 0 + j][r];
                    float ov = acc[mt * 4 + 2 + j][r];
                    cxr[(mt * 2 + j) * 4 + r] *= fast_sigmoid(fv);
                    og[mt * 2 + j][r] = (half_t)ov;
                }
        __builtin_amdgcn_sched_barrier(0);

        // ---- pass B: gates (i,g); acc init CHUNKED ----
#pragma unroll
        for (int fc = 0; fc < 16; fc += 4) {
#pragma unroll
            for (int f = fc; f < fc + 4; ++f) {
                half4v u = *reinterpret_cast<const half4v*>(
                    &lds_xp[((w * 32 + 16 + f) * 64 + l) * 4]);
#pragma unroll
                for (int r = 0; r < 4; ++r) acc[f][r] = (float)u[r];
            }
            __builtin_amdgcn_sched_barrier(0);
        }
        gemm_pass(acc, lds_hx, Whh_s, w2, w2 + 1, 32 + w2, 33 + w2,
                  lm, lg, l, nocw);

        __syncthreads();   // all waves finished reading lds_hx(t)

        // epiB: cell update; write hx(t+1) into lds_hx (f16, swizzled)
#pragma unroll
        for (int mt = 0; mt < 4; ++mt)
#pragma unroll
            for (int j = 0; j < 2; ++j)
#pragma unroll
                for (int r = 0; r < 4; ++r) {
                    const int ci = (mt * 2 + j) * 4 + r;
                    float iv = acc[mt * 4 + 0 + j][r];
                    float gv = acc[mt * 4 + 2 + j][r];
                    float cxn = cxr[ci] + fast_sigmoid(iv) * fast_tanh(gv);
                    cxr[ci] = cxn;
                    float so = fast_sigmoid((float)og[mt * 2 + j][r]);
                    float h = so * fast_tanh(cxn);
                    int p  = mt * 16 + lg * 4 + r;
                    int cc = w * 32 + j * 16 + lm;
                    lds_hx[p * 256 + (cc ^ ((p & 7) << 4))] = (half_t)h;
                }
        __syncthreads();   // hx(t+1) visible to all (next gemmA + head)
    }

    // ---- final head (t = 15) ----
    {
        const float* wl = W_lin + ho * 256 + hq * 64;
        asm volatile("" : "+v"(wl));
        float s = 0.0f;
#pragma unroll 2
        for (int cb = 0; cb < 16; ++cb) {
            int c0 = hq * 64 + cb * 4;
            half4v u = *reinterpret_cast<const half4v*>(
                &lds_hx[ph * 256 + (c0 ^ ((ph & 7) << 4))]);
            float4 wv = *reinterpret_cast<const float4*>(wl + cb * 4);
            float h0 = (float)u[0], h1 = (float)u[1];
            float h2 = (float)u[2], h3 = (float)u[3];
            s += fmaxf(h0, 0.01f * h0) * wv.x;
            s += fmaxf(h1, 0.01f * h1) * wv.y;
            s += fmaxf(h2, 0.01f * h2) * wv.z;
            s += fmaxf(h3, 0.01f * h3) * wv.w;
        }
        s += __shfl_xor(s, 1);
        s += __shfl_xor(s, 2);
        if (hq == 0)
            out[((size_t)(row0 + ph) * 16 + 15) * 2 + ho] =
                s + (ho ? blin1 : blin0);
    }
}

// ---------------------------------------------------------------------------
extern "C" void kernel_launch(void* const* d_in, const int* in_sizes, int n_in,
                              void* d_out, int out_size, void* d_ws, size_t ws_size,
                              hipStream_t stream)
{
    const float* x    = (const float*)d_in[0];
    const float* hx   = (const float*)d_in[1];
    const float* cx   = (const float*)d_in[2];
    const float* Wih  = (const float*)d_in[3];
    const float* Whh  = (const float*)d_in[4];
    const float* bih  = (const float*)d_in[5];
    const float* bhh  = (const float*)d_in[6];
    const float* Wlin = (const float*)d_in[7];
    const float* blin = (const float*)d_in[8];
    float* out = (float*)d_out;

    half_t* wih_s = (half_t*)d_ws;             // 512 KB
    half_t* whh_s = wih_s + 1024 * 256;        // 512 KB

    shuffle_w_kernel<<<512, 64, 0, stream>>>(Wih, wih_s);
    shuffle_w_kernel<<<512, 64, 0, stream>>>(Whh, whh_s);
    lstm_kernel<<<200, 512, 0, stream>>>(x, hx, cx, bih, bhh, Wlin, blin,
                                         wih_s, whh_s, out);
}